// Round 5
// baseline (255.073 us; speedup 1.0000x reference)
//
#include <hip/hip_runtime.h>
#include <cstdint>

// CSM_62216896250023: emb gather (16384,7,1024) -> 4 stacked depthwise seq-convs
// with sigmoid, seq 7->6->5->3->1, out (16384,1024) f32.
//
// R5 == R4 with the compile fix (__builtin_nontemporal_store needs a clang
// ext_vector_type, not HIP's float4 struct).
//
// R4 rationale: R1-R3 all pinned at ~95-101us with identical FETCH regardless
// of VALU load -> latency-bound; compiler serializes register-destination
// gathers (VGPR 36-44). global_load_lds (width=16) holds NO VGPRs while in
// flight, so all 7 row-gathers per wave stay outstanding. One 4KB emb row ==
// one block (256 lanes x float4); each wave owns a 1KB channel slice; LDS dest
// is the HW-native wave-uniform-base + lane*16. 28KB LDS -> 5 blocks/CU
// (20 waves TLP). Output stored nontemporally to kill RFO fetch.

constexpr int EMBED = 1024;
constexpr int SEQ   = 7;

typedef float f2 __attribute__((ext_vector_type(2)));
typedef float f4 __attribute__((ext_vector_type(4)));

__device__ __forceinline__ f2 sig2(f2 y) {
    // y = -log2(e) * preact;  sigmoid = 1/(1 + 2^y)
    f2 u;
    u.x = __builtin_amdgcn_exp2f(y.x);
    u.y = __builtin_amdgcn_exp2f(y.y);
    f2 d = u + (f2){1.0f, 1.0f};
    f2 r;
    r.x = __builtin_amdgcn_rcpf(d.x);
    r.y = __builtin_amdgcn_rcpf(d.y);
    return r;
}

__global__ __launch_bounds__(256) void CSM_62216896250023_kernel(
    const int*   __restrict__ X,
    const float* __restrict__ emb,
    const float* __restrict__ c1,
    const float* __restrict__ c2,
    const float* __restrict__ c3,
    const float* __restrict__ c4,
    float*       __restrict__ out)
{
    __shared__ float smem[SEQ * EMBED];          // 28 KB: token t at smem + t*1024

    const int b = blockIdx.x;
    const int e = threadIdx.x << 2;              // float offset; == wid*256 + lane*4

    // Stage all 7 gathered rows into LDS asynchronously. Zero VGPR cost while
    // in flight -> 7-deep MLP per wave guaranteed. LDS dest must be the
    // wave-uniform base (smem + t*1024 + wid*256 floats); HW adds lane*16B,
    // which lands each lane exactly at smem + t*1024 + e.
#pragma unroll
    for (int t = 0; t < SEQ; ++t) {
        const int id = X[b * SEQ + t];           // uniform -> s_load
        const float* g = emb + (size_t)id * EMBED + e;
        float* l = smem + t * EMBED + (e & ~255);   // wave-uniform slice base
        __builtin_amdgcn_global_load_lds(
            (const __attribute__((address_space(1))) void*)g,
            (__attribute__((address_space(3))) void*)l,
            16, 0, 0);
    }

    // Overlap the gather latency with weight loads + prescale by -log2(e).
    const float NL2E = -1.44269504088896f;
    f2 k1[2][2], k2[2][2], k3[3][2], k4[3][2];
#pragma unroll
    for (int t = 0; t < 2; ++t) {
        float4 f = *(const float4*)(c1 + t * EMBED + e);
        k1[t][0] = (f2){f.x * NL2E, f.y * NL2E};
        k1[t][1] = (f2){f.z * NL2E, f.w * NL2E};
        f = *(const float4*)(c2 + t * EMBED + e);
        k2[t][0] = (f2){f.x * NL2E, f.y * NL2E};
        k2[t][1] = (f2){f.z * NL2E, f.w * NL2E};
    }
#pragma unroll
    for (int t = 0; t < 3; ++t) {
        float4 f = *(const float4*)(c3 + t * EMBED + e);
        k3[t][0] = (f2){f.x * NL2E, f.y * NL2E};
        k3[t][1] = (f2){f.z * NL2E, f.w * NL2E};
        f = *(const float4*)(c4 + t * EMBED + e);
        k4[t][0] = (f2){f.x * NL2E, f.y * NL2E};
        k4[t][1] = (f2){f.z * NL2E, f.w * NL2E};
    }

    __syncthreads();    // drains vmcnt -> staged data visible

    // Read back own slice (stride-16B ds_read_b128: 2-way bank alias = free).
    f2 v[SEQ][2];
#pragma unroll
    for (int t = 0; t < SEQ; ++t) {
        const float4 f = *(const float4*)(smem + t * EMBED + e);
        v[t][0] = (f2){f.x, f.y};
        v[t][1] = (f2){f.z, f.w};
    }

    f2 o[2];
#pragma unroll
    for (int p = 0; p < 2; ++p) {
        f2 h1[6];
#pragma unroll
        for (int l = 0; l < 6; ++l)
            h1[l] = sig2(v[l][p] * k1[0][p] + v[l + 1][p] * k1[1][p]);
        f2 h2[5];
#pragma unroll
        for (int l = 0; l < 5; ++l)
            h2[l] = sig2(h1[l] * k2[0][p] + h1[l + 1] * k2[1][p]);
        f2 h3[3];
#pragma unroll
        for (int l = 0; l < 3; ++l)
            h3[l] = sig2(h2[l] * k3[0][p] + h2[l + 1] * k3[1][p] + h2[l + 2] * k3[2][p]);
        o[p] = sig2(h3[0] * k4[0][p] + h3[1] * k4[1][p] + h3[2] * k4[2][p]);
    }

    f4 of;
    of.x = o[0].x; of.y = o[0].y; of.z = o[1].x; of.w = o[1].y;
    __builtin_nontemporal_store(of, (f4*)(out + (size_t)b * EMBED + e));
}

extern "C" void kernel_launch(void* const* d_in, const int* in_sizes, int n_in,
                              void* d_out, int out_size, void* d_ws, size_t ws_size,
                              hipStream_t stream) {
    const int*   X   = (const int*)d_in[0];
    const float* emb = (const float*)d_in[1];
    const float* c1  = (const float*)d_in[2];
    const float* c2  = (const float*)d_in[3];
    const float* c3  = (const float*)d_in[4];
    const float* c4  = (const float*)d_in[5];
    float* out = (float*)d_out;

    const int batch = in_sizes[0] / SEQ;        // 16384
    CSM_62216896250023_kernel<<<batch, 256, 0, stream>>>(X, emb, c1, c2, c3, c4, out);
}